// Round 1
// baseline (900.275 us; speedup 1.0000x reference)
//
#include <hip/hip_runtime.h>

// GCN 3-layer: h = relu(segsum(x[src],dst) @ W + b) x2, then no-relu output layer.
// Identity used: segsum(h[src]) @ W == segsum((h@W)[src])  (segment_sum is linear).
// Pipeline:
//   CSR build (counting sort by dst)  -- once per launch, deterministic work
//   bufA = features @ W0              -- mm128
//   bufB = relu(agg(bufA) + b0)       -- agg128<bias+relu>
//   bufA = bufB @ W1                  -- mm128
//   bufB = relu(agg(bufA) + b1)       -- agg128<bias+relu>
//   bufA = agg(bufB)                  -- agg128<plain>
//   out  = bufA @ W2 + b2             -- mmout (128 -> 40)

#define FEAT 128

// ---------------- CSR build ----------------

__global__ void count_kernel(const int* __restrict__ dst, int* __restrict__ counts,
                             int n_edges) {
    int i = blockIdx.x * blockDim.x + threadIdx.x;
    if (i < n_edges) atomicAdd(&counts[dst[i]], 1);
}

__global__ __launch_bounds__(1024) void scan_kernel(const int* __restrict__ counts,
                                                    int* __restrict__ offsets,
                                                    int* __restrict__ cursor, int n) {
    __shared__ int sdata[1024];
    const int t = threadIdx.x;
    const int C = (n + 1023) / 1024;
    const int base = t * C;
    const int end = min(base + C, n);
    int sum = 0;
    for (int i = base; i < end; ++i) sum += counts[i];
    sdata[t] = sum;
    __syncthreads();
    // Hillis-Steele inclusive scan over 1024 thread partials
    for (int off = 1; off < 1024; off <<= 1) {
        int v = (t >= off) ? sdata[t - off] : 0;
        __syncthreads();
        sdata[t] += v;
        __syncthreads();
    }
    int running = sdata[t] - sum;  // exclusive prefix
    for (int i = base; i < end; ++i) {
        int c = counts[i];
        offsets[i] = running;
        cursor[i]  = running;
        running += c;
    }
    if (t == 1023) offsets[n] = sdata[1023];
}

__global__ void scatter_kernel(const int* __restrict__ src, const int* __restrict__ dst,
                               int* __restrict__ cursor, int* __restrict__ csr_src,
                               int n_edges) {
    int i = blockIdx.x * blockDim.x + threadIdx.x;
    if (i < n_edges) {
        int d = dst[i];
        int pos = atomicAdd(&cursor[d], 1);
        csr_src[pos] = src[i];
    }
}

// ---------------- aggregation: Y[n] = sum_{e: dst=n} X[csr_src[e]] ----------------
// 32 lanes per node (float4 each => 128 floats), 8 nodes per 256-thread block.
// EPI: 0 = plain, 1 = +bias then relu

template <int EPI>
__global__ __launch_bounds__(256) void agg128_kernel(const float* __restrict__ X,
                                                     const int* __restrict__ offsets,
                                                     const int* __restrict__ csr_src,
                                                     const float* __restrict__ bias,
                                                     float* __restrict__ Y, int n) {
    const int t = threadIdx.x;
    const int g = t >> 5;
    const int lane = t & 31;
    const int node = blockIdx.x * 8 + g;
    if (node >= n) return;
    const int e0 = offsets[node];
    const int e1 = offsets[node + 1];
    const int c4 = lane * 4;
    float4 acc = make_float4(0.f, 0.f, 0.f, 0.f);
    int e = e0;
    for (; e + 1 < e1; e += 2) {
        int s0 = csr_src[e];
        int s1 = csr_src[e + 1];
        float4 v0 = *(const float4*)(X + (size_t)s0 * FEAT + c4);
        float4 v1 = *(const float4*)(X + (size_t)s1 * FEAT + c4);
        acc.x += v0.x + v1.x;
        acc.y += v0.y + v1.y;
        acc.z += v0.z + v1.z;
        acc.w += v0.w + v1.w;
    }
    if (e < e1) {
        int s0 = csr_src[e];
        float4 v0 = *(const float4*)(X + (size_t)s0 * FEAT + c4);
        acc.x += v0.x; acc.y += v0.y; acc.z += v0.z; acc.w += v0.w;
    }
    if (EPI == 1) {
        float4 b = *(const float4*)(bias + c4);
        acc.x = fmaxf(acc.x + b.x, 0.f);
        acc.y = fmaxf(acc.y + b.y, 0.f);
        acc.z = fmaxf(acc.z + b.z, 0.f);
        acc.w = fmaxf(acc.w + b.w, 0.f);
    }
    *(float4*)(Y + (size_t)node * FEAT + c4) = acc;
}

// ---------------- mm128: C[N,128] = A[N,128] @ W[128,128] ----------------
// 32 rows/block, 256 threads, thread = 4 rows x 4 cols register tile.
// W staged in LDS in 32-row k-tiles (16 KB), A rows staged padded (16.9 KB).

__global__ __launch_bounds__(256) void mm128_kernel(const float* __restrict__ A,
                                                    const float* __restrict__ W,
                                                    float* __restrict__ C, int n) {
    __shared__ __align__(16) float Wl[32][128];
    __shared__ __align__(16) float Al[32][132];
    const int t = threadIdx.x;
    const int row0 = blockIdx.x * 32;

    for (int i = t; i < 1024; i += 256) {
        int r = i >> 5, c = (i & 31) * 4;
        int row = row0 + r;
        float4 v = make_float4(0.f, 0.f, 0.f, 0.f);
        if (row < n) v = *(const float4*)(A + (size_t)row * FEAT + c);
        Al[r][c] = v.x; Al[r][c + 1] = v.y; Al[r][c + 2] = v.z; Al[r][c + 3] = v.w;
    }

    const int cg = t & 31;     // col group: 4 cols
    const int rg = t >> 5;     // row group: 4 rows
    float4 acc0 = make_float4(0.f, 0.f, 0.f, 0.f);
    float4 acc1 = acc0, acc2 = acc0, acc3 = acc0;

    for (int kt = 0; kt < 4; ++kt) {
        __syncthreads();
        for (int i = t; i < 1024; i += 256) {
            int r = i >> 5, c = (i & 31) * 4;
            *(float4*)&Wl[r][c] = *(const float4*)(W + (size_t)(kt * 32 + r) * FEAT + c);
        }
        __syncthreads();
#pragma unroll
        for (int kk = 0; kk < 32; ++kk) {
            float4 w = *(float4*)&Wl[kk][cg * 4];
            int k = kt * 32 + kk;
            float a0 = Al[rg * 4 + 0][k];
            float a1 = Al[rg * 4 + 1][k];
            float a2 = Al[rg * 4 + 2][k];
            float a3 = Al[rg * 4 + 3][k];
            acc0.x += a0 * w.x; acc0.y += a0 * w.y; acc0.z += a0 * w.z; acc0.w += a0 * w.w;
            acc1.x += a1 * w.x; acc1.y += a1 * w.y; acc1.z += a1 * w.z; acc1.w += a1 * w.w;
            acc2.x += a2 * w.x; acc2.y += a2 * w.y; acc2.z += a2 * w.z; acc2.w += a2 * w.w;
            acc3.x += a3 * w.x; acc3.y += a3 * w.y; acc3.z += a3 * w.z; acc3.w += a3 * w.w;
        }
    }

    const int rbase = row0 + rg * 4;
    if (rbase + 0 < n) *(float4*)&C[(size_t)(rbase + 0) * FEAT + cg * 4] = acc0;
    if (rbase + 1 < n) *(float4*)&C[(size_t)(rbase + 1) * FEAT + cg * 4] = acc1;
    if (rbase + 2 < n) *(float4*)&C[(size_t)(rbase + 2) * FEAT + cg * 4] = acc2;
    if (rbase + 3 < n) *(float4*)&C[(size_t)(rbase + 3) * FEAT + cg * 4] = acc3;
}

// ---------------- mmout: C[N,40] = A[N,128] @ W[128,40] + b ----------------

__global__ __launch_bounds__(256) void mmout_kernel(const float* __restrict__ A,
                                                    const float* __restrict__ W,
                                                    const float* __restrict__ bias,
                                                    float* __restrict__ C, int n) {
    __shared__ float Wl[128][40];   // 20 KB
    __shared__ __align__(16) float Al[32][132];
    const int t = threadIdx.x;
    const int row0 = blockIdx.x * 32;

    for (int i = t; i < 128 * 40; i += 256) Wl[i / 40][i % 40] = W[i];
    for (int i = t; i < 1024; i += 256) {
        int r = i >> 5, c = (i & 31) * 4;
        int row = row0 + r;
        float4 v = make_float4(0.f, 0.f, 0.f, 0.f);
        if (row < n) v = *(const float4*)(A + (size_t)row * FEAT + c);
        Al[r][c] = v.x; Al[r][c + 1] = v.y; Al[r][c + 2] = v.z; Al[r][c + 3] = v.w;
    }
    __syncthreads();

    const int rl = t >> 3;          // 0..31
    const int c0 = (t & 7) * 5;     // 0,5,...,35
    const int row = row0 + rl;
    float acc[5] = {0.f, 0.f, 0.f, 0.f, 0.f};
    for (int k = 0; k < 128; ++k) {
        float a = Al[rl][k];
#pragma unroll
        for (int j = 0; j < 5; ++j) acc[j] += a * Wl[k][c0 + j];
    }
    if (row < n) {
#pragma unroll
        for (int j = 0; j < 5; ++j) C[(size_t)row * 40 + c0 + j] = acc[j] + bias[c0 + j];
    }
}

// ---------------- launch ----------------

extern "C" void kernel_launch(void* const* d_in, const int* in_sizes, int n_in,
                              void* d_out, int out_size, void* d_ws, size_t ws_size,
                              hipStream_t stream) {
    const float* features = (const float*)d_in[0];
    const int* src = (const int*)d_in[1];
    const int* dst = (const int*)d_in[2];
    const float* W0 = (const float*)d_in[3];
    const float* b0 = (const float*)d_in[4];
    const float* W1 = (const float*)d_in[5];
    const float* b1 = (const float*)d_in[6];
    const float* W2 = (const float*)d_in[7];
    const float* b2 = (const float*)d_in[8];
    float* out = (float*)d_out;

    const int n_nodes = in_sizes[0] / FEAT;
    const int n_edges = in_sizes[1];

    char* p = (char*)d_ws;
    auto alloc = [&](size_t bytes) {
        char* q = p;
        p += (bytes + 255) & ~(size_t)255;
        return q;
    };
    float* bufA   = (float*)alloc((size_t)n_nodes * FEAT * 4);
    float* bufB   = (float*)alloc((size_t)n_nodes * FEAT * 4);
    int* counts   = (int*)alloc((size_t)n_nodes * 4);
    int* offsets  = (int*)alloc((size_t)(n_nodes + 1) * 4);
    int* cursor   = (int*)alloc((size_t)n_nodes * 4);
    int* csr      = (int*)alloc((size_t)n_edges * 4);

    // CSR build
    hipMemsetAsync(counts, 0, (size_t)n_nodes * 4, stream);
    count_kernel<<<(n_edges + 255) / 256, 256, 0, stream>>>(dst, counts, n_edges);
    scan_kernel<<<1, 1024, 0, stream>>>(counts, offsets, cursor, n_nodes);
    scatter_kernel<<<(n_edges + 255) / 256, 256, 0, stream>>>(src, dst, cursor, csr, n_edges);

    const int mm_grid = (n_nodes + 31) / 32;
    const int agg_grid = (n_nodes + 7) / 8;

    // layer 0
    mm128_kernel<<<mm_grid, 256, 0, stream>>>(features, W0, bufA, n_nodes);
    agg128_kernel<1><<<agg_grid, 256, 0, stream>>>(bufA, offsets, csr, b0, bufB, n_nodes);
    // layer 1
    mm128_kernel<<<mm_grid, 256, 0, stream>>>(bufB, W1, bufA, n_nodes);
    agg128_kernel<1><<<agg_grid, 256, 0, stream>>>(bufA, offsets, csr, b1, bufB, n_nodes);
    // layer 2 (aggregate-first, then 128->40 matmul with bias)
    agg128_kernel<0><<<agg_grid, 256, 0, stream>>>(bufB, offsets, csr, nullptr, bufA, n_nodes);
    mmout_kernel<<<mm_grid, 256, 0, stream>>>(bufA, W2, b2, out, n_nodes);
}

// Round 2
// 634.834 us; speedup vs baseline: 1.4181x; 1.4181x over previous
//
#include <hip/hip_runtime.h>

// GCN 3-layer: h = relu(segsum(x[src],dst) @ W + b) x2, then no-relu output layer.
// Identity used (linearity): segsum(h[src]) @ W == segsum((h@W)[src]).
// Pipeline:
//   CSR build: count (atomic histogram) -> 3-phase multi-block scan -> scatter
//   bufA = features @ W0              -- mm128
//   bufB = relu(agg128(bufA) + b0)
//   bufA = bufB @ W1                  -- mm128
//   bufB = relu(agg128(bufA) + b1)
//   bufC = bufB @ W2   (no bias)      -- mm40   [bufC aliases bufA]
//   out  = agg40(bufC) + b2

#define FEAT 128

// ---------------- CSR build ----------------

__global__ void count_kernel(const int* __restrict__ dst, int* __restrict__ counts,
                             int n_edges) {
    int i = blockIdx.x * blockDim.x + threadIdx.x;
    if (i < n_edges) atomicAdd(&counts[dst[i]], 1);
}

// 3-phase exclusive scan over counts[n]. CHUNK=1024 elems/block, 256 thr x 4.
// Assumes nblocks <= 256 (n <= 262144).

__global__ __launch_bounds__(256) void scan_part1(const int* __restrict__ counts,
                                                  int* __restrict__ bsum, int n) {
    __shared__ int sdata[256];
    const int t = threadIdx.x;
    const int base = blockIdx.x * 1024 + t * 4;
    int s = 0;
#pragma unroll
    for (int j = 0; j < 4; ++j) {
        int i = base + j;
        if (i < n) s += counts[i];
    }
    sdata[t] = s;
    for (int off = 128; off > 0; off >>= 1) {
        __syncthreads();
        if (t < off) sdata[t] += sdata[t + off];
    }
    if (t == 0) bsum[blockIdx.x] = sdata[0];
}

__global__ __launch_bounds__(256) void scan_part2(int* __restrict__ bsum,
                                                  int* __restrict__ offsets,
                                                  int nb, int n) {
    __shared__ int sdata[256];
    const int t = threadIdx.x;
    const int v = (t < nb) ? bsum[t] : 0;
    sdata[t] = v;
    __syncthreads();
    for (int off = 1; off < 256; off <<= 1) {
        int u = (t >= off) ? sdata[t - off] : 0;
        __syncthreads();
        sdata[t] += u;
        __syncthreads();
    }
    if (t < nb) bsum[t] = sdata[t] - v;  // exclusive block prefix
    if (t == 255) offsets[n] = sdata[255];
}

__global__ __launch_bounds__(256) void scan_part3(const int* __restrict__ counts,
                                                  const int* __restrict__ bsum,
                                                  int* __restrict__ offsets,
                                                  int* __restrict__ cursor, int n) {
    __shared__ int sdata[256];
    const int t = threadIdx.x;
    const int base = blockIdx.x * 1024 + t * 4;
    int c[4];
    int s = 0;
#pragma unroll
    for (int j = 0; j < 4; ++j) {
        int i = base + j;
        c[j] = (i < n) ? counts[i] : 0;
        s += c[j];
    }
    sdata[t] = s;
    __syncthreads();
    for (int off = 1; off < 256; off <<= 1) {
        int u = (t >= off) ? sdata[t - off] : 0;
        __syncthreads();
        sdata[t] += u;
        __syncthreads();
    }
    int pre = bsum[blockIdx.x] + sdata[t] - s;
#pragma unroll
    for (int j = 0; j < 4; ++j) {
        int i = base + j;
        if (i < n) {
            offsets[i] = pre;
            cursor[i] = pre;
            pre += c[j];
        }
    }
}

__global__ void scatter_kernel(const int* __restrict__ src, const int* __restrict__ dst,
                               int* __restrict__ cursor, int* __restrict__ csr_src,
                               int n_edges) {
    int i = blockIdx.x * blockDim.x + threadIdx.x;
    if (i < n_edges) {
        int d = dst[i];
        int pos = atomicAdd(&cursor[d], 1);
        csr_src[pos] = src[i];
    }
}

// ---------------- agg128: Y[n,128] = sum_{e: dst=n} X[csr[e],128] (+bias,relu) ----
// 32 lanes per node (float4 each), 8 nodes per 256-thread block.

template <int EPI>  // 0 = plain, 1 = +bias then relu
__global__ __launch_bounds__(256) void agg128_kernel(const float* __restrict__ X,
                                                     const int* __restrict__ offsets,
                                                     const int* __restrict__ csr_src,
                                                     const float* __restrict__ bias,
                                                     float* __restrict__ Y, int n) {
    const int t = threadIdx.x;
    const int g = t >> 5;
    const int lane = t & 31;
    const int node = blockIdx.x * 8 + g;
    if (node >= n) return;
    const int e0 = offsets[node];
    const int e1 = offsets[node + 1];
    const int c4 = lane * 4;
    float4 acc = make_float4(0.f, 0.f, 0.f, 0.f);
    int e = e0;
    for (; e + 1 < e1; e += 2) {
        int s0 = csr_src[e];
        int s1 = csr_src[e + 1];
        float4 v0 = *(const float4*)(X + (size_t)s0 * FEAT + c4);
        float4 v1 = *(const float4*)(X + (size_t)s1 * FEAT + c4);
        acc.x += v0.x + v1.x;
        acc.y += v0.y + v1.y;
        acc.z += v0.z + v1.z;
        acc.w += v0.w + v1.w;
    }
    if (e < e1) {
        int s0 = csr_src[e];
        float4 v0 = *(const float4*)(X + (size_t)s0 * FEAT + c4);
        acc.x += v0.x; acc.y += v0.y; acc.z += v0.z; acc.w += v0.w;
    }
    if (EPI == 1) {
        float4 b = *(const float4*)(bias + c4);
        acc.x = fmaxf(acc.x + b.x, 0.f);
        acc.y = fmaxf(acc.y + b.y, 0.f);
        acc.z = fmaxf(acc.z + b.z, 0.f);
        acc.w = fmaxf(acc.w + b.w, 0.f);
    }
    *(float4*)(Y + (size_t)node * FEAT + c4) = acc;
}

// ---------------- agg40: Y[n,40] = sum X[csr[e],40] + bias ----------------
// 16-lane group per node, lanes 0..9 each own a float4 (10x4 = 40 floats).

__global__ __launch_bounds__(256) void agg40_kernel(const float* __restrict__ X,
                                                    const int* __restrict__ offsets,
                                                    const int* __restrict__ csr_src,
                                                    const float* __restrict__ bias,
                                                    float* __restrict__ Y, int n) {
    const int t = threadIdx.x;
    const int g = t >> 4;
    const int lane = t & 15;
    const int node = blockIdx.x * 16 + g;
    if (node >= n || lane >= 10) return;
    const int e0 = offsets[node];
    const int e1 = offsets[node + 1];
    const int c4 = lane * 4;
    float4 acc = make_float4(0.f, 0.f, 0.f, 0.f);
    int e = e0;
    for (; e + 1 < e1; e += 2) {
        int s0 = csr_src[e];
        int s1 = csr_src[e + 1];
        float4 v0 = *(const float4*)(X + (size_t)s0 * 40 + c4);
        float4 v1 = *(const float4*)(X + (size_t)s1 * 40 + c4);
        acc.x += v0.x + v1.x;
        acc.y += v0.y + v1.y;
        acc.z += v0.z + v1.z;
        acc.w += v0.w + v1.w;
    }
    if (e < e1) {
        int s0 = csr_src[e];
        float4 v0 = *(const float4*)(X + (size_t)s0 * 40 + c4);
        acc.x += v0.x; acc.y += v0.y; acc.z += v0.z; acc.w += v0.w;
    }
    float4 b = *(const float4*)(bias + c4);
    acc.x += b.x; acc.y += b.y; acc.z += b.z; acc.w += b.w;
    *(float4*)(Y + (size_t)node * 40 + c4) = acc;
}

// ---------------- mm128: C[N,128] = A[N,128] @ W[128,128] ----------------

__global__ __launch_bounds__(256) void mm128_kernel(const float* __restrict__ A,
                                                    const float* __restrict__ W,
                                                    float* __restrict__ C, int n) {
    __shared__ __align__(16) float Wl[32][128];
    __shared__ __align__(16) float Al[32][132];
    const int t = threadIdx.x;
    const int row0 = blockIdx.x * 32;

    for (int i = t; i < 1024; i += 256) {
        int r = i >> 5, c = (i & 31) * 4;
        int row = row0 + r;
        float4 v = make_float4(0.f, 0.f, 0.f, 0.f);
        if (row < n) v = *(const float4*)(A + (size_t)row * FEAT + c);
        Al[r][c] = v.x; Al[r][c + 1] = v.y; Al[r][c + 2] = v.z; Al[r][c + 3] = v.w;
    }

    const int cg = t & 31;
    const int rg = t >> 5;
    float4 acc0 = make_float4(0.f, 0.f, 0.f, 0.f);
    float4 acc1 = acc0, acc2 = acc0, acc3 = acc0;

    for (int kt = 0; kt < 4; ++kt) {
        __syncthreads();
        for (int i = t; i < 1024; i += 256) {
            int r = i >> 5, c = (i & 31) * 4;
            *(float4*)&Wl[r][c] = *(const float4*)(W + (size_t)(kt * 32 + r) * FEAT + c);
        }
        __syncthreads();
#pragma unroll
        for (int kk = 0; kk < 32; ++kk) {
            float4 w = *(float4*)&Wl[kk][cg * 4];
            int k = kt * 32 + kk;
            float a0 = Al[rg * 4 + 0][k];
            float a1 = Al[rg * 4 + 1][k];
            float a2 = Al[rg * 4 + 2][k];
            float a3 = Al[rg * 4 + 3][k];
            acc0.x += a0 * w.x; acc0.y += a0 * w.y; acc0.z += a0 * w.z; acc0.w += a0 * w.w;
            acc1.x += a1 * w.x; acc1.y += a1 * w.y; acc1.z += a1 * w.z; acc1.w += a1 * w.w;
            acc2.x += a2 * w.x; acc2.y += a2 * w.y; acc2.z += a2 * w.z; acc2.w += a2 * w.w;
            acc3.x += a3 * w.x; acc3.y += a3 * w.y; acc3.z += a3 * w.z; acc3.w += a3 * w.w;
        }
    }

    const int rbase = row0 + rg * 4;
    if (rbase + 0 < n) *(float4*)&C[(size_t)(rbase + 0) * FEAT + cg * 4] = acc0;
    if (rbase + 1 < n) *(float4*)&C[(size_t)(rbase + 1) * FEAT + cg * 4] = acc1;
    if (rbase + 2 < n) *(float4*)&C[(size_t)(rbase + 2) * FEAT + cg * 4] = acc2;
    if (rbase + 3 < n) *(float4*)&C[(size_t)(rbase + 3) * FEAT + cg * 4] = acc3;
}

// ---------------- mm40: C[N,40] = A[N,128] @ W[128,40]  (no bias) ----------------

__global__ __launch_bounds__(256) void mm40_kernel(const float* __restrict__ A,
                                                   const float* __restrict__ W,
                                                   float* __restrict__ C, int n) {
    __shared__ float Wl[128][40];  // 20 KB
    __shared__ __align__(16) float Al[32][132];
    const int t = threadIdx.x;
    const int row0 = blockIdx.x * 32;

    for (int i = t; i < 128 * 40; i += 256) Wl[i / 40][i % 40] = W[i];
    for (int i = t; i < 1024; i += 256) {
        int r = i >> 5, c = (i & 31) * 4;
        int row = row0 + r;
        float4 v = make_float4(0.f, 0.f, 0.f, 0.f);
        if (row < n) v = *(const float4*)(A + (size_t)row * FEAT + c);
        Al[r][c] = v.x; Al[r][c + 1] = v.y; Al[r][c + 2] = v.z; Al[r][c + 3] = v.w;
    }
    __syncthreads();

    const int rl = t >> 3;
    const int c0 = (t & 7) * 5;
    const int row = row0 + rl;
    float acc[5] = {0.f, 0.f, 0.f, 0.f, 0.f};
    for (int k = 0; k < 128; ++k) {
        float a = Al[rl][k];
#pragma unroll
        for (int j = 0; j < 5; ++j) acc[j] += a * Wl[k][c0 + j];
    }
    if (row < n) {
#pragma unroll
        for (int j = 0; j < 5; ++j) C[(size_t)row * 40 + c0 + j] = acc[j];
    }
}

// ---------------- launch ----------------

extern "C" void kernel_launch(void* const* d_in, const int* in_sizes, int n_in,
                              void* d_out, int out_size, void* d_ws, size_t ws_size,
                              hipStream_t stream) {
    const float* features = (const float*)d_in[0];
    const int* src = (const int*)d_in[1];
    const int* dst = (const int*)d_in[2];
    const float* W0 = (const float*)d_in[3];
    const float* b0 = (const float*)d_in[4];
    const float* W1 = (const float*)d_in[5];
    const float* b1 = (const float*)d_in[6];
    const float* W2 = (const float*)d_in[7];
    const float* b2 = (const float*)d_in[8];
    float* out = (float*)d_out;

    const int n_nodes = in_sizes[0] / FEAT;
    const int n_edges = in_sizes[1];

    char* p = (char*)d_ws;
    auto alloc = [&](size_t bytes) {
        char* q = p;
        p += (bytes + 255) & ~(size_t)255;
        return q;
    };
    float* bufA   = (float*)alloc((size_t)n_nodes * FEAT * 4);
    float* bufB   = (float*)alloc((size_t)n_nodes * FEAT * 4);
    int* counts   = (int*)alloc((size_t)n_nodes * 4);
    int* offsets  = (int*)alloc((size_t)(n_nodes + 1) * 4);
    int* cursor   = (int*)alloc((size_t)n_nodes * 4);
    int* csr      = (int*)alloc((size_t)n_edges * 4);
    int* bsum     = (int*)alloc(1024);
    float* bufC   = bufA;  // alias: [N,40] fits in bufA's [N,128] region

    const int nscan = (n_nodes + 1023) / 1024;

    // CSR build
    hipMemsetAsync(counts, 0, (size_t)n_nodes * 4, stream);
    count_kernel<<<(n_edges + 255) / 256, 256, 0, stream>>>(dst, counts, n_edges);
    scan_part1<<<nscan, 256, 0, stream>>>(counts, bsum, n_nodes);
    scan_part2<<<1, 256, 0, stream>>>(bsum, offsets, nscan, n_nodes);
    scan_part3<<<nscan, 256, 0, stream>>>(counts, bsum, offsets, cursor, n_nodes);
    scatter_kernel<<<(n_edges + 255) / 256, 256, 0, stream>>>(src, dst, cursor, csr, n_edges);

    const int mm_grid = (n_nodes + 31) / 32;
    const int agg_grid = (n_nodes + 7) / 8;
    const int agg40_grid = (n_nodes + 15) / 16;

    // layer 0
    mm128_kernel<<<mm_grid, 256, 0, stream>>>(features, W0, bufA, n_nodes);
    agg128_kernel<1><<<agg_grid, 256, 0, stream>>>(bufA, offsets, csr, b0, bufB, n_nodes);
    // layer 1
    mm128_kernel<<<mm_grid, 256, 0, stream>>>(bufB, W1, bufA, n_nodes);
    agg128_kernel<1><<<agg_grid, 256, 0, stream>>>(bufA, offsets, csr, b1, bufB, n_nodes);
    // layer 2: matmul-first (128->40, linearity), then aggregate + bias
    mm40_kernel<<<mm_grid, 256, 0, stream>>>(bufB, W2, bufC, n_nodes);
    agg40_kernel<<<agg40_grid, 256, 0, stream>>>(bufC, offsets, csr, b2, out, n_nodes);
}

// Round 3
// 494.914 us; speedup vs baseline: 1.8191x; 1.2827x over previous
//
#include <hip/hip_runtime.h>

// GCN 3-layer: h = relu(segsum(x[src],dst) @ W + b) x2, then no-relu output layer.
// Identity used (linearity): segsum(h[src]) @ W == segsum((h@W)[src]).
//
// CSR build is BINNED to avoid cross-XCD write amplification (R2: scatter wrote
// 105 MB for a 6.4 MB payload):
//   bin_count:   LDS histogram over 256-node bins -> global bin_counts
//   bin_scan:    1-block exclusive scan over bins -> bin_offsets / bin_cursor
//   bin_scatter: LDS hist + per-(block,bin) cursor reservation -> packed ebuf
//                (edges grouped by bin; writes are bin-contiguous runs)
//   csr_build:   1 block per bin: LDS per-node hist + scan -> exact CSR in the
//                bin's contiguous 16 KB region (one XCD, one writeback)
// Then:
//   bufA = features @ W0; bufB = relu(agg128(bufA)+b0)
//   bufA = bufB @ W1;     bufB = relu(agg128(bufA)+b1)
//   bufC = bufB @ W2;     out  = agg40(bufC)+b2

#define FEAT 128
#define BIN_SHIFT 8            // 256 nodes per bin
#define MAX_BINS 512           // n_nodes <= 131072
#define SCAT_TILE 8192

// ---------------- CSR build ----------------

__global__ __launch_bounds__(256) void bin_count(const int* __restrict__ dst,
                                                 int* __restrict__ bin_counts,
                                                 int n_edges, int nb) {
    __shared__ int hist[MAX_BINS];
    const int t = threadIdx.x;
    for (int i = t; i < nb; i += 256) hist[i] = 0;
    __syncthreads();
    for (int i = blockIdx.x * 256 + t; i < n_edges; i += gridDim.x * 256)
        atomicAdd(&hist[dst[i] >> BIN_SHIFT], 1);
    __syncthreads();
    for (int i = t; i < nb; i += 256) {
        int h = hist[i];
        if (h) atomicAdd(&bin_counts[i], h);
    }
}

__global__ __launch_bounds__(512) void bin_scan(const int* __restrict__ bin_counts,
                                                int* __restrict__ bin_offsets,
                                                int* __restrict__ bin_cursor,
                                                int* __restrict__ offsets,
                                                int nb, int n_nodes, int n_edges) {
    __shared__ int sc[512];
    const int t = threadIdx.x;
    const int v = (t < nb) ? bin_counts[t] : 0;
    sc[t] = v;
    __syncthreads();
    for (int off = 1; off < 512; off <<= 1) {
        int u = (t >= off) ? sc[t - off] : 0;
        __syncthreads();
        sc[t] += u;
        __syncthreads();
    }
    if (t <= nb) {
        int e = (t < nb) ? (sc[t] - v) : n_edges;  // exclusive prefix; [nb] = total
        bin_offsets[t] = e;
        if (t < nb) bin_cursor[t] = e;
    }
    if (t == 0) offsets[n_nodes] = n_edges;
}

__global__ __launch_bounds__(256) void bin_scatter(const int* __restrict__ src,
                                                   const int* __restrict__ dst,
                                                   int* __restrict__ bin_cursor,
                                                   int* __restrict__ ebuf,
                                                   int n_edges, int nb) {
    __shared__ int hist[MAX_BINS];
    __shared__ int cur[MAX_BINS];
    const int t = threadIdx.x;
    const int lo = blockIdx.x * SCAT_TILE;
    const int hi = min(lo + SCAT_TILE, n_edges);
    for (int i = t; i < nb; i += 256) hist[i] = 0;
    __syncthreads();
    for (int i = lo + t; i < hi; i += 256) atomicAdd(&hist[dst[i] >> BIN_SHIFT], 1);
    __syncthreads();
    for (int i = t; i < nb; i += 256) {
        int h = hist[i];
        cur[i] = h ? atomicAdd(&bin_cursor[i], h) : 0;
    }
    __syncthreads();
    for (int i = lo + t; i < hi; i += 256) {
        int d = dst[i];
        int b = d >> BIN_SHIFT;
        int pos = atomicAdd(&cur[b], 1);
        ebuf[pos] = ((d & 255) << 24) | src[i];
    }
}

__global__ __launch_bounds__(256) void csr_build(const int* __restrict__ ebuf,
                                                 const int* __restrict__ bin_offsets,
                                                 int* __restrict__ offsets,
                                                 int* __restrict__ csr,
                                                 int n_nodes) {
    __shared__ int cnt[256];
    __shared__ int sc[256];
    __shared__ int cur[256];
    const int b = blockIdx.x;
    const int t = threadIdx.x;
    const int lo = bin_offsets[b];
    const int hi = bin_offsets[b + 1];
    cnt[t] = 0;
    __syncthreads();
    for (int e = lo + t; e < hi; e += 256)
        atomicAdd(&cnt[((unsigned)ebuf[e]) >> 24], 1);
    __syncthreads();
    const int x = cnt[t];
    sc[t] = x;
    __syncthreads();
    for (int off = 1; off < 256; off <<= 1) {
        int u = (t >= off) ? sc[t - off] : 0;
        __syncthreads();
        sc[t] += u;
        __syncthreads();
    }
    const int start = lo + sc[t] - x;
    cur[t] = start;
    const int node = (b << BIN_SHIFT) + t;
    if (node < n_nodes) offsets[node] = start;
    __syncthreads();
    for (int e = lo + t; e < hi; e += 256) {
        int p = ebuf[e];
        int dl = ((unsigned)p) >> 24;
        int pos = atomicAdd(&cur[dl], 1);
        csr[pos] = p & 0x00FFFFFF;
    }
}

// ---------------- agg128: Y[n,128] = sum_{e: dst=n} X[csr[e],128] (+bias,relu) ----
// 32 lanes per node (float4 each), 8 nodes per 256-thread block.

template <int EPI>  // 0 = plain, 1 = +bias then relu
__global__ __launch_bounds__(256) void agg128_kernel(const float* __restrict__ X,
                                                     const int* __restrict__ offsets,
                                                     const int* __restrict__ csr_src,
                                                     const float* __restrict__ bias,
                                                     float* __restrict__ Y, int n) {
    const int t = threadIdx.x;
    const int g = t >> 5;
    const int lane = t & 31;
    const int node = blockIdx.x * 8 + g;
    if (node >= n) return;
    const int e0 = offsets[node];
    const int e1 = offsets[node + 1];
    const int c4 = lane * 4;
    float4 acc = make_float4(0.f, 0.f, 0.f, 0.f);
    int e = e0;
    for (; e + 1 < e1; e += 2) {
        int s0 = csr_src[e];
        int s1 = csr_src[e + 1];
        float4 v0 = *(const float4*)(X + (size_t)s0 * FEAT + c4);
        float4 v1 = *(const float4*)(X + (size_t)s1 * FEAT + c4);
        acc.x += v0.x + v1.x;
        acc.y += v0.y + v1.y;
        acc.z += v0.z + v1.z;
        acc.w += v0.w + v1.w;
    }
    if (e < e1) {
        int s0 = csr_src[e];
        float4 v0 = *(const float4*)(X + (size_t)s0 * FEAT + c4);
        acc.x += v0.x; acc.y += v0.y; acc.z += v0.z; acc.w += v0.w;
    }
    if (EPI == 1) {
        float4 b = *(const float4*)(bias + c4);
        acc.x = fmaxf(acc.x + b.x, 0.f);
        acc.y = fmaxf(acc.y + b.y, 0.f);
        acc.z = fmaxf(acc.z + b.z, 0.f);
        acc.w = fmaxf(acc.w + b.w, 0.f);
    }
    *(float4*)(Y + (size_t)node * FEAT + c4) = acc;
}

// ---------------- agg40: Y[n,40] = sum X[csr[e],40] + bias ----------------

__global__ __launch_bounds__(256) void agg40_kernel(const float* __restrict__ X,
                                                    const int* __restrict__ offsets,
                                                    const int* __restrict__ csr_src,
                                                    const float* __restrict__ bias,
                                                    float* __restrict__ Y, int n) {
    const int t = threadIdx.x;
    const int g = t >> 4;
    const int lane = t & 15;
    const int node = blockIdx.x * 16 + g;
    if (node >= n || lane >= 10) return;
    const int e0 = offsets[node];
    const int e1 = offsets[node + 1];
    const int c4 = lane * 4;
    float4 acc = make_float4(0.f, 0.f, 0.f, 0.f);
    int e = e0;
    for (; e + 1 < e1; e += 2) {
        int s0 = csr_src[e];
        int s1 = csr_src[e + 1];
        float4 v0 = *(const float4*)(X + (size_t)s0 * 40 + c4);
        float4 v1 = *(const float4*)(X + (size_t)s1 * 40 + c4);
        acc.x += v0.x + v1.x;
        acc.y += v0.y + v1.y;
        acc.z += v0.z + v1.z;
        acc.w += v0.w + v1.w;
    }
    if (e < e1) {
        int s0 = csr_src[e];
        float4 v0 = *(const float4*)(X + (size_t)s0 * 40 + c4);
        acc.x += v0.x; acc.y += v0.y; acc.z += v0.z; acc.w += v0.w;
    }
    float4 b = *(const float4*)(bias + c4);
    acc.x += b.x; acc.y += b.y; acc.z += b.z; acc.w += b.w;
    *(float4*)(Y + (size_t)node * 40 + c4) = acc;
}

// ---------------- mm128: C[N,128] = A[N,128] @ W[128,128] ----------------

__global__ __launch_bounds__(256) void mm128_kernel(const float* __restrict__ A,
                                                    const float* __restrict__ W,
                                                    float* __restrict__ C, int n) {
    __shared__ __align__(16) float Wl[32][128];
    __shared__ __align__(16) float Al[32][132];
    const int t = threadIdx.x;
    const int row0 = blockIdx.x * 32;

    for (int i = t; i < 1024; i += 256) {
        int r = i >> 5, c = (i & 31) * 4;
        int row = row0 + r;
        float4 v = make_float4(0.f, 0.f, 0.f, 0.f);
        if (row < n) v = *(const float4*)(A + (size_t)row * FEAT + c);
        Al[r][c] = v.x; Al[r][c + 1] = v.y; Al[r][c + 2] = v.z; Al[r][c + 3] = v.w;
    }

    const int cg = t & 31;
    const int rg = t >> 5;
    float4 acc0 = make_float4(0.f, 0.f, 0.f, 0.f);
    float4 acc1 = acc0, acc2 = acc0, acc3 = acc0;

    for (int kt = 0; kt < 4; ++kt) {
        __syncthreads();
        for (int i = t; i < 1024; i += 256) {
            int r = i >> 5, c = (i & 31) * 4;
            *(float4*)&Wl[r][c] = *(const float4*)(W + (size_t)(kt * 32 + r) * FEAT + c);
        }
        __syncthreads();
#pragma unroll
        for (int kk = 0; kk < 32; ++kk) {
            float4 w = *(float4*)&Wl[kk][cg * 4];
            int k = kt * 32 + kk;
            float a0 = Al[rg * 4 + 0][k];
            float a1 = Al[rg * 4 + 1][k];
            float a2 = Al[rg * 4 + 2][k];
            float a3 = Al[rg * 4 + 3][k];
            acc0.x += a0 * w.x; acc0.y += a0 * w.y; acc0.z += a0 * w.z; acc0.w += a0 * w.w;
            acc1.x += a1 * w.x; acc1.y += a1 * w.y; acc1.z += a1 * w.z; acc1.w += a1 * w.w;
            acc2.x += a2 * w.x; acc2.y += a2 * w.y; acc2.z += a2 * w.z; acc2.w += a2 * w.w;
            acc3.x += a3 * w.x; acc3.y += a3 * w.y; acc3.z += a3 * w.z; acc3.w += a3 * w.w;
        }
    }

    const int rbase = row0 + rg * 4;
    if (rbase + 0 < n) *(float4*)&C[(size_t)(rbase + 0) * FEAT + cg * 4] = acc0;
    if (rbase + 1 < n) *(float4*)&C[(size_t)(rbase + 1) * FEAT + cg * 4] = acc1;
    if (rbase + 2 < n) *(float4*)&C[(size_t)(rbase + 2) * FEAT + cg * 4] = acc2;
    if (rbase + 3 < n) *(float4*)&C[(size_t)(rbase + 3) * FEAT + cg * 4] = acc3;
}

// ---------------- mm40: C[N,40] = A[N,128] @ W[128,40]  (no bias) ----------------

__global__ __launch_bounds__(256) void mm40_kernel(const float* __restrict__ A,
                                                   const float* __restrict__ W,
                                                   float* __restrict__ C, int n) {
    __shared__ float Wl[128][40];  // 20 KB
    __shared__ __align__(16) float Al[32][132];
    const int t = threadIdx.x;
    const int row0 = blockIdx.x * 32;

    for (int i = t; i < 128 * 40; i += 256) Wl[i / 40][i % 40] = W[i];
    for (int i = t; i < 1024; i += 256) {
        int r = i >> 5, c = (i & 31) * 4;
        int row = row0 + r;
        float4 v = make_float4(0.f, 0.f, 0.f, 0.f);
        if (row < n) v = *(const float4*)(A + (size_t)row * FEAT + c);
        Al[r][c] = v.x; Al[r][c + 1] = v.y; Al[r][c + 2] = v.z; Al[r][c + 3] = v.w;
    }
    __syncthreads();

    const int rl = t >> 3;
    const int c0 = (t & 7) * 5;
    const int row = row0 + rl;
    float acc[5] = {0.f, 0.f, 0.f, 0.f, 0.f};
    for (int k = 0; k < 128; ++k) {
        float a = Al[rl][k];
#pragma unroll
        for (int j = 0; j < 5; ++j) acc[j] += a * Wl[k][c0 + j];
    }
    if (row < n) {
#pragma unroll
        for (int j = 0; j < 5; ++j) C[(size_t)row * 40 + c0 + j] = acc[j];
    }
}

// ---------------- launch ----------------

extern "C" void kernel_launch(void* const* d_in, const int* in_sizes, int n_in,
                              void* d_out, int out_size, void* d_ws, size_t ws_size,
                              hipStream_t stream) {
    const float* features = (const float*)d_in[0];
    const int* src = (const int*)d_in[1];
    const int* dst = (const int*)d_in[2];
    const float* W0 = (const float*)d_in[3];
    const float* b0 = (const float*)d_in[4];
    const float* W1 = (const float*)d_in[5];
    const float* b1 = (const float*)d_in[6];
    const float* W2 = (const float*)d_in[7];
    const float* b2 = (const float*)d_in[8];
    float* out = (float*)d_out;

    const int n_nodes = in_sizes[0] / FEAT;
    const int n_edges = in_sizes[1];
    const int nb = (n_nodes + 255) >> BIN_SHIFT;

    char* p = (char*)d_ws;
    auto alloc = [&](size_t bytes) {
        char* q = p;
        p += (bytes + 255) & ~(size_t)255;
        return q;
    };
    float* bufA     = (float*)alloc((size_t)n_nodes * FEAT * 4);
    float* bufB     = (float*)alloc((size_t)n_nodes * FEAT * 4);
    int* offsets    = (int*)alloc((size_t)(n_nodes + 1) * 4);
    int* csr        = (int*)alloc((size_t)n_edges * 4);
    int* ebuf       = (int*)alloc((size_t)n_edges * 4);
    int* bin_counts = (int*)alloc(MAX_BINS * 4);
    int* bin_offs   = (int*)alloc((MAX_BINS + 1) * 4);
    int* bin_cursor = (int*)alloc(MAX_BINS * 4);
    float* bufC     = bufA;  // alias: [N,40] fits in bufA's [N,128] region

    // CSR build (binned)
    hipMemsetAsync(bin_counts, 0, MAX_BINS * 4, stream);
    bin_count<<<256, 256, 0, stream>>>(dst, bin_counts, n_edges, nb);
    bin_scan<<<1, 512, 0, stream>>>(bin_counts, bin_offs, bin_cursor, offsets,
                                    nb, n_nodes, n_edges);
    bin_scatter<<<(n_edges + SCAT_TILE - 1) / SCAT_TILE, 256, 0, stream>>>(
        src, dst, bin_cursor, ebuf, n_edges, nb);
    csr_build<<<nb, 256, 0, stream>>>(ebuf, bin_offs, offsets, csr, n_nodes);

    const int mm_grid = (n_nodes + 31) / 32;
    const int agg_grid = (n_nodes + 7) / 8;
    const int agg40_grid = (n_nodes + 15) / 16;

    // layer 0
    mm128_kernel<<<mm_grid, 256, 0, stream>>>(features, W0, bufA, n_nodes);
    agg128_kernel<1><<<agg_grid, 256, 0, stream>>>(bufA, offsets, csr, b0, bufB, n_nodes);
    // layer 1
    mm128_kernel<<<mm_grid, 256, 0, stream>>>(bufB, W1, bufA, n_nodes);
    agg128_kernel<1><<<agg_grid, 256, 0, stream>>>(bufA, offsets, csr, b1, bufB, n_nodes);
    // layer 2: matmul-first (128->40, linearity), then aggregate + bias
    mm40_kernel<<<mm_grid, 256, 0, stream>>>(bufB, W2, bufC, n_nodes);
    agg40_kernel<<<agg40_grid, 256, 0, stream>>>(bufC, offsets, csr, b2, out, n_nodes);
}

// Round 4
// 373.655 us; speedup vs baseline: 2.4094x; 1.3245x over previous
//
#include <hip/hip_runtime.h>
#include <hip/hip_bf16.h>

// GCN 3-layer. Identity used (linearity): segsum(h[src]) @ W == segsum((h@W)[src]).
// R4: store mm outputs (the gathered operands) in bf16 -> halves gather bytes.
//     fp32 accumulate; one RNE rounding per layer (error budget: thr=49.3, R3=4.0).
//     4-deep unrolled gather loop for MLP.
//
// Pipeline:
//   CSR build (binned, R3)
//   bufA(bf16) = features @ W0;  bufB(f32) = relu(agg128(bufA)+b0)
//   bufA(bf16) = bufB @ W1;      bufB(f32) = relu(agg128(bufA)+b1)
//   bufC(bf16) = bufB @ W2;      out(f32)  = agg40(bufC)+b2

#define FEAT 128
#define BIN_SHIFT 8            // 256 nodes per bin
#define MAX_BINS 512           // n_nodes <= 131072
#define SCAT_TILE 8192

// ---------------- helpers ----------------

__device__ __forceinline__ void bf16x8_add(float* a, uint4 v) {
    a[0] += __uint_as_float(v.x << 16);
    a[1] += __uint_as_float(v.x & 0xffff0000u);
    a[2] += __uint_as_float(v.y << 16);
    a[3] += __uint_as_float(v.y & 0xffff0000u);
    a[4] += __uint_as_float(v.z << 16);
    a[5] += __uint_as_float(v.z & 0xffff0000u);
    a[6] += __uint_as_float(v.w << 16);
    a[7] += __uint_as_float(v.w & 0xffff0000u);
}

__device__ __forceinline__ unsigned pack_bf16(float a, float b) {
    union { __hip_bfloat162 h; unsigned u; } c;
    c.h.x = __float2bfloat16(a);
    c.h.y = __float2bfloat16(b);
    return c.u;
}

// ---------------- CSR build ----------------

__global__ __launch_bounds__(256) void bin_count(const int* __restrict__ dst,
                                                 int* __restrict__ bin_counts,
                                                 int n_edges, int nb) {
    __shared__ int hist[MAX_BINS];
    const int t = threadIdx.x;
    for (int i = t; i < nb; i += 256) hist[i] = 0;
    __syncthreads();
    const int n4 = n_edges >> 2;
    for (int i = blockIdx.x * 256 + t; i < n4; i += gridDim.x * 256) {
        int4 d = ((const int4*)dst)[i];
        atomicAdd(&hist[d.x >> BIN_SHIFT], 1);
        atomicAdd(&hist[d.y >> BIN_SHIFT], 1);
        atomicAdd(&hist[d.z >> BIN_SHIFT], 1);
        atomicAdd(&hist[d.w >> BIN_SHIFT], 1);
    }
    if (blockIdx.x == 0 && t < (n_edges & 3))
        atomicAdd(&hist[dst[n4 * 4 + t] >> BIN_SHIFT], 1);
    __syncthreads();
    for (int i = t; i < nb; i += 256) {
        int h = hist[i];
        if (h) atomicAdd(&bin_counts[i], h);
    }
}

__global__ __launch_bounds__(512) void bin_scan(const int* __restrict__ bin_counts,
                                                int* __restrict__ bin_offsets,
                                                int* __restrict__ bin_cursor,
                                                int* __restrict__ offsets,
                                                int nb, int n_nodes, int n_edges) {
    __shared__ int sc[512];
    const int t = threadIdx.x;
    const int v = (t < nb) ? bin_counts[t] : 0;
    sc[t] = v;
    __syncthreads();
    for (int off = 1; off < 512; off <<= 1) {
        int u = (t >= off) ? sc[t - off] : 0;
        __syncthreads();
        sc[t] += u;
        __syncthreads();
    }
    if (t <= nb) {
        int e = (t < nb) ? (sc[t] - v) : n_edges;
        bin_offsets[t] = e;
        if (t < nb) bin_cursor[t] = e;
    }
    if (t == 0) offsets[n_nodes] = n_edges;
}

__global__ __launch_bounds__(256) void bin_scatter(const int* __restrict__ src,
                                                   const int* __restrict__ dst,
                                                   int* __restrict__ bin_cursor,
                                                   int* __restrict__ ebuf,
                                                   int n_edges, int nb) {
    __shared__ int hist[MAX_BINS];
    __shared__ int cur[MAX_BINS];
    const int t = threadIdx.x;
    const int lo = blockIdx.x * SCAT_TILE;
    const int hi = min(lo + SCAT_TILE, n_edges);
    for (int i = t; i < nb; i += 256) hist[i] = 0;
    __syncthreads();
    for (int i = lo + t; i < hi; i += 256) atomicAdd(&hist[dst[i] >> BIN_SHIFT], 1);
    __syncthreads();
    for (int i = t; i < nb; i += 256) {
        int h = hist[i];
        cur[i] = h ? atomicAdd(&bin_cursor[i], h) : 0;
    }
    __syncthreads();
    for (int i = lo + t; i < hi; i += 256) {
        int d = dst[i];
        int b = d >> BIN_SHIFT;
        int pos = atomicAdd(&cur[b], 1);
        ebuf[pos] = ((d & 255) << 24) | src[i];
    }
}

__global__ __launch_bounds__(256) void csr_build(const int* __restrict__ ebuf,
                                                 const int* __restrict__ bin_offsets,
                                                 int* __restrict__ offsets,
                                                 int* __restrict__ csr,
                                                 int n_nodes) {
    __shared__ int cnt[256];
    __shared__ int sc[256];
    __shared__ int cur[256];
    const int b = blockIdx.x;
    const int t = threadIdx.x;
    const int lo = bin_offsets[b];
    const int hi = bin_offsets[b + 1];
    cnt[t] = 0;
    __syncthreads();
    for (int e = lo + t; e < hi; e += 256)
        atomicAdd(&cnt[((unsigned)ebuf[e]) >> 24], 1);
    __syncthreads();
    const int x = cnt[t];
    sc[t] = x;
    __syncthreads();
    for (int off = 1; off < 256; off <<= 1) {
        int u = (t >= off) ? sc[t - off] : 0;
        __syncthreads();
        sc[t] += u;
        __syncthreads();
    }
    const int start = lo + sc[t] - x;
    cur[t] = start;
    const int node = (b << BIN_SHIFT) + t;
    if (node < n_nodes) offsets[node] = start;
    __syncthreads();
    for (int e = lo + t; e < hi; e += 256) {
        int p = ebuf[e];
        int dl = ((unsigned)p) >> 24;
        int pos = atomicAdd(&cur[dl], 1);
        csr[pos] = p & 0x00FFFFFF;
    }
}

// ------- agg128_bf16: Y[n,128](f32) = sum_{e} X[csr[e],128](bf16)  (+bias,relu) ----
// 16 lanes per node (uint4 = 8 bf16 each), 16 nodes per 256-thread block.

template <int EPI>  // 0 = plain, 1 = +bias then relu
__global__ __launch_bounds__(256) void agg128_bf16(const unsigned* __restrict__ X,
                                                   const int* __restrict__ offsets,
                                                   const int* __restrict__ csr_src,
                                                   const float* __restrict__ bias,
                                                   float* __restrict__ Y, int n) {
    const int t = threadIdx.x;
    const int g = t >> 4;
    const int lane = t & 15;
    const int node = blockIdx.x * 16 + g;
    if (node >= n) return;
    const int e0 = offsets[node];
    const int e1 = offsets[node + 1];
    const int cu = lane * 4;  // uint offset within 64-uint row
    float acc[8] = {0.f, 0.f, 0.f, 0.f, 0.f, 0.f, 0.f, 0.f};
    int e = e0;
    for (; e + 3 < e1; e += 4) {
        int s0 = csr_src[e];
        int s1 = csr_src[e + 1];
        int s2 = csr_src[e + 2];
        int s3 = csr_src[e + 3];
        uint4 v0 = *(const uint4*)(X + (size_t)s0 * 64 + cu);
        uint4 v1 = *(const uint4*)(X + (size_t)s1 * 64 + cu);
        uint4 v2 = *(const uint4*)(X + (size_t)s2 * 64 + cu);
        uint4 v3 = *(const uint4*)(X + (size_t)s3 * 64 + cu);
        bf16x8_add(acc, v0);
        bf16x8_add(acc, v1);
        bf16x8_add(acc, v2);
        bf16x8_add(acc, v3);
    }
    for (; e < e1; ++e) {
        int s0 = csr_src[e];
        uint4 v0 = *(const uint4*)(X + (size_t)s0 * 64 + cu);
        bf16x8_add(acc, v0);
    }
    if (EPI == 1) {
        float4 b0 = *(const float4*)(bias + lane * 8);
        float4 b1 = *(const float4*)(bias + lane * 8 + 4);
        acc[0] = fmaxf(acc[0] + b0.x, 0.f);
        acc[1] = fmaxf(acc[1] + b0.y, 0.f);
        acc[2] = fmaxf(acc[2] + b0.z, 0.f);
        acc[3] = fmaxf(acc[3] + b0.w, 0.f);
        acc[4] = fmaxf(acc[4] + b1.x, 0.f);
        acc[5] = fmaxf(acc[5] + b1.y, 0.f);
        acc[6] = fmaxf(acc[6] + b1.z, 0.f);
        acc[7] = fmaxf(acc[7] + b1.w, 0.f);
    }
    float* yp = Y + (size_t)node * FEAT + lane * 8;
    *(float4*)yp = make_float4(acc[0], acc[1], acc[2], acc[3]);
    *(float4*)(yp + 4) = make_float4(acc[4], acc[5], acc[6], acc[7]);
}

// ------- agg40_bf16: out[n,40](f32) = sum X[csr[e],40](bf16) + bias ----------
// 8 lanes per node, lanes 0..4 own uint4 (8 bf16) each; 32 nodes per block.

__global__ __launch_bounds__(256) void agg40_bf16(const unsigned* __restrict__ X,
                                                  const int* __restrict__ offsets,
                                                  const int* __restrict__ csr_src,
                                                  const float* __restrict__ bias,
                                                  float* __restrict__ Y, int n) {
    const int t = threadIdx.x;
    const int g = t >> 3;
    const int lane = t & 7;
    const int node = blockIdx.x * 32 + g;
    if (node >= n) return;
    const int e0 = offsets[node];
    const int e1 = offsets[node + 1];
    const bool active = lane < 5;
    const int cu = lane * 4;  // uint offset within 20-uint row
    float acc[8] = {0.f, 0.f, 0.f, 0.f, 0.f, 0.f, 0.f, 0.f};
    int e = e0;
    for (; e + 3 < e1; e += 4) {
        int s0 = csr_src[e];
        int s1 = csr_src[e + 1];
        int s2 = csr_src[e + 2];
        int s3 = csr_src[e + 3];
        if (active) {
            uint4 v0 = *(const uint4*)(X + (size_t)s0 * 20 + cu);
            uint4 v1 = *(const uint4*)(X + (size_t)s1 * 20 + cu);
            uint4 v2 = *(const uint4*)(X + (size_t)s2 * 20 + cu);
            uint4 v3 = *(const uint4*)(X + (size_t)s3 * 20 + cu);
            bf16x8_add(acc, v0);
            bf16x8_add(acc, v1);
            bf16x8_add(acc, v2);
            bf16x8_add(acc, v3);
        }
    }
    for (; e < e1; ++e) {
        int s0 = csr_src[e];
        if (active) {
            uint4 v0 = *(const uint4*)(X + (size_t)s0 * 20 + cu);
            bf16x8_add(acc, v0);
        }
    }
    if (active) {
        float4 b0 = *(const float4*)(bias + lane * 8);
        float4 b1 = *(const float4*)(bias + lane * 8 + 4);
        float* yp = Y + (size_t)node * 40 + lane * 8;
        *(float4*)yp = make_float4(acc[0] + b0.x, acc[1] + b0.y,
                                   acc[2] + b0.z, acc[3] + b0.w);
        *(float4*)(yp + 4) = make_float4(acc[4] + b1.x, acc[5] + b1.y,
                                         acc[6] + b1.z, acc[7] + b1.w);
    }
}

// ---------------- mm128: C[N,128](bf16) = A[N,128](f32) @ W[128,128](f32) --------

__global__ __launch_bounds__(256) void mm128_kernel(const float* __restrict__ A,
                                                    const float* __restrict__ W,
                                                    unsigned* __restrict__ C, int n) {
    __shared__ __align__(16) float Wl[32][128];
    __shared__ __align__(16) float Al[32][132];
    const int t = threadIdx.x;
    const int row0 = blockIdx.x * 32;

    for (int i = t; i < 1024; i += 256) {
        int r = i >> 5, c = (i & 31) * 4;
        int row = row0 + r;
        float4 v = make_float4(0.f, 0.f, 0.f, 0.f);
        if (row < n) v = *(const float4*)(A + (size_t)row * FEAT + c);
        Al[r][c] = v.x; Al[r][c + 1] = v.y; Al[r][c + 2] = v.z; Al[r][c + 3] = v.w;
    }

    const int cg = t & 31;
    const int rg = t >> 5;
    float4 acc0 = make_float4(0.f, 0.f, 0.f, 0.f);
    float4 acc1 = acc0, acc2 = acc0, acc3 = acc0;

    for (int kt = 0; kt < 4; ++kt) {
        __syncthreads();
        for (int i = t; i < 1024; i += 256) {
            int r = i >> 5, c = (i & 31) * 4;
            *(float4*)&Wl[r][c] = *(const float4*)(W + (size_t)(kt * 32 + r) * FEAT + c);
        }
        __syncthreads();
#pragma unroll
        for (int kk = 0; kk < 32; ++kk) {
            float4 w = *(float4*)&Wl[kk][cg * 4];
            int k = kt * 32 + kk;
            float a0 = Al[rg * 4 + 0][k];
            float a1 = Al[rg * 4 + 1][k];
            float a2 = Al[rg * 4 + 2][k];
            float a3 = Al[rg * 4 + 3][k];
            acc0.x += a0 * w.x; acc0.y += a0 * w.y; acc0.z += a0 * w.z; acc0.w += a0 * w.w;
            acc1.x += a1 * w.x; acc1.y += a1 * w.y; acc1.z += a1 * w.z; acc1.w += a1 * w.w;
            acc2.x += a2 * w.x; acc2.y += a2 * w.y; acc2.z += a2 * w.z; acc2.w += a2 * w.w;
            acc3.x += a3 * w.x; acc3.y += a3 * w.y; acc3.z += a3 * w.z; acc3.w += a3 * w.w;
        }
    }

    const int rbase = row0 + rg * 4;
    if (rbase + 0 < n)
        *(uint2*)(C + (size_t)(rbase + 0) * 64 + cg * 2) =
            make_uint2(pack_bf16(acc0.x, acc0.y), pack_bf16(acc0.z, acc0.w));
    if (rbase + 1 < n)
        *(uint2*)(C + (size_t)(rbase + 1) * 64 + cg * 2) =
            make_uint2(pack_bf16(acc1.x, acc1.y), pack_bf16(acc1.z, acc1.w));
    if (rbase + 2 < n)
        *(uint2*)(C + (size_t)(rbase + 2) * 64 + cg * 2) =
            make_uint2(pack_bf16(acc2.x, acc2.y), pack_bf16(acc2.z, acc2.w));
    if (rbase + 3 < n)
        *(uint2*)(C + (size_t)(rbase + 3) * 64 + cg * 2) =
            make_uint2(pack_bf16(acc3.x, acc3.y), pack_bf16(acc3.z, acc3.w));
}

// ---------------- mm40: C[N,40](bf16) = A[N,128](f32) @ W[128,40](f32) ----------

__global__ __launch_bounds__(256) void mm40_kernel(const float* __restrict__ A,
                                                   const float* __restrict__ W,
                                                   unsigned* __restrict__ C, int n) {
    __shared__ float Wl[128][40];              // 20 KB
    __shared__ __align__(16) float Al[32][132];
    __shared__ __align__(16) float Cl[32][40]; // 5 KB bounce for packed bf16 stores
    const int t = threadIdx.x;
    const int row0 = blockIdx.x * 32;

    for (int i = t; i < 128 * 40; i += 256) Wl[i / 40][i % 40] = W[i];
    for (int i = t; i < 1024; i += 256) {
        int r = i >> 5, c = (i & 31) * 4;
        int row = row0 + r;
        float4 v = make_float4(0.f, 0.f, 0.f, 0.f);
        if (row < n) v = *(const float4*)(A + (size_t)row * FEAT + c);
        Al[r][c] = v.x; Al[r][c + 1] = v.y; Al[r][c + 2] = v.z; Al[r][c + 3] = v.w;
    }
    __syncthreads();

    const int rl = t >> 3;
    const int c0 = (t & 7) * 5;
    float acc[5] = {0.f, 0.f, 0.f, 0.f, 0.f};
    for (int k = 0; k < 128; ++k) {
        float a = Al[rl][k];
#pragma unroll
        for (int j = 0; j < 5; ++j) acc[j] += a * Wl[k][c0 + j];
    }
#pragma unroll
    for (int j = 0; j < 5; ++j) Cl[rl][c0 + j] = acc[j];
    __syncthreads();

    // pack 32 rows x 40 cols -> bf16: 5 uint4 per row, 160 uint4 total
    for (int i = t; i < 160; i += 256) {
        int r = i / 5, q = i % 5;
        int row = row0 + r;
        if (row >= n) continue;
        const float* s = &Cl[r][q * 8];
        uint4 o = make_uint4(pack_bf16(s[0], s[1]), pack_bf16(s[2], s[3]),
                             pack_bf16(s[4], s[5]), pack_bf16(s[6], s[7]));
        *(uint4*)(C + (size_t)row * 20 + q * 4) = o;
    }
}

// ---------------- launch ----------------

extern "C" void kernel_launch(void* const* d_in, const int* in_sizes, int n_in,
                              void* d_out, int out_size, void* d_ws, size_t ws_size,
                              hipStream_t stream) {
    const float* features = (const float*)d_in[0];
    const int* src = (const int*)d_in[1];
    const int* dst = (const int*)d_in[2];
    const float* W0 = (const float*)d_in[3];
    const float* b0 = (const float*)d_in[4];
    const float* W1 = (const float*)d_in[5];
    const float* b1 = (const float*)d_in[6];
    const float* W2 = (const float*)d_in[7];
    const float* b2 = (const float*)d_in[8];
    float* out = (float*)d_out;

    const int n_nodes = in_sizes[0] / FEAT;
    const int n_edges = in_sizes[1];
    const int nb = (n_nodes + 255) >> BIN_SHIFT;

    char* p = (char*)d_ws;
    auto alloc = [&](size_t bytes) {
        char* q = p;
        p += (bytes + 255) & ~(size_t)255;
        return q;
    };
    unsigned* bufA  = (unsigned*)alloc((size_t)n_nodes * FEAT * 2);  // bf16 [N,128]
    float* bufB     = (float*)alloc((size_t)n_nodes * FEAT * 4);     // f32  [N,128]
    int* offsets    = (int*)alloc((size_t)(n_nodes + 1) * 4);
    int* csr        = (int*)alloc((size_t)n_edges * 4);
    int* ebuf       = (int*)alloc((size_t)n_edges * 4);
    int* bin_counts = (int*)alloc(MAX_BINS * 4);
    int* bin_offs   = (int*)alloc((MAX_BINS + 1) * 4);
    int* bin_cursor = (int*)alloc(MAX_BINS * 4);
    unsigned* bufC  = bufA;  // alias: bf16 [N,40] fits in bufA's region

    // CSR build (binned)
    hipMemsetAsync(bin_counts, 0, MAX_BINS * 4, stream);
    bin_count<<<256, 256, 0, stream>>>(dst, bin_counts, n_edges, nb);
    bin_scan<<<1, 512, 0, stream>>>(bin_counts, bin_offs, bin_cursor, offsets,
                                    nb, n_nodes, n_edges);
    bin_scatter<<<(n_edges + SCAT_TILE - 1) / SCAT_TILE, 256, 0, stream>>>(
        src, dst, bin_cursor, ebuf, n_edges, nb);
    csr_build<<<nb, 256, 0, stream>>>(ebuf, bin_offs, offsets, csr, n_nodes);

    const int mm_grid = (n_nodes + 31) / 32;
    const int agg_grid = (n_nodes + 15) / 16;
    const int agg40_grid = (n_nodes + 31) / 32;

    // layer 0
    mm128_kernel<<<mm_grid, 256, 0, stream>>>(features, W0, bufA, n_nodes);
    agg128_bf16<1><<<agg_grid, 256, 0, stream>>>(bufA, offsets, csr, b0, bufB, n_nodes);
    // layer 1
    mm128_kernel<<<mm_grid, 256, 0, stream>>>(bufB, W1, bufA, n_nodes);
    agg128_bf16<1><<<agg_grid, 256, 0, stream>>>(bufA, offsets, csr, b1, bufB, n_nodes);
    // layer 2: matmul-first (128->40, linearity), then aggregate + bias
    mm40_kernel<<<mm_grid, 256, 0, stream>>>(bufB, W2, bufC, n_nodes);
    agg40_bf16<<<agg40_grid, 256, 0, stream>>>(bufC, offsets, csr, b2, out, n_nodes);
}

// Round 5
// 285.472 us; speedup vs baseline: 3.1536x; 1.3089x over previous
//
#include <hip/hip_runtime.h>
#include <hip/hip_bf16.h>

// GCN 3-layer. Linearity: segsum(h[src]) @ W == segsum((h@W)[src]).
// R5: mm128 -> MFMA bf16 (16x16x32), W pre-transposed to [n][k] bf16;
//     agg outputs stored bf16 (halves agg writes + mm fetches).
// Pipeline:
//   CSR build (binned)              prep_w: Wt0/Wt1[n][k] bf16
//   bufA(bf16) = features @ Wt0 (MFMA);  bufB(bf16) = relu(agg128(bufA)+b0)
//   bufA(bf16) = bufB @ Wt1 (MFMA);      bufB(bf16) = relu(agg128(bufA)+b1)
//   bufC(bf16) = bufB @ W2 (vector);     out(f32)   = agg40(bufC)+b2

#define FEAT 128
#define BIN_SHIFT 8
#define MAX_BINS 512
#define SCAT_TILE 8192

typedef __attribute__((ext_vector_type(8))) short bf16x8_t;
typedef __attribute__((ext_vector_type(4))) float f32x4_t;

// ---------------- helpers ----------------

__device__ __forceinline__ void bf16x8_add(float* a, uint4 v) {
    a[0] += __uint_as_float(v.x << 16);
    a[1] += __uint_as_float(v.x & 0xffff0000u);
    a[2] += __uint_as_float(v.y << 16);
    a[3] += __uint_as_float(v.y & 0xffff0000u);
    a[4] += __uint_as_float(v.z << 16);
    a[5] += __uint_as_float(v.z & 0xffff0000u);
    a[6] += __uint_as_float(v.w << 16);
    a[7] += __uint_as_float(v.w & 0xffff0000u);
}

__device__ __forceinline__ unsigned pack_bf16(float a, float b) {
    union { __hip_bfloat162 h; unsigned u; } c;
    c.h.x = __float2bfloat16(a);
    c.h.y = __float2bfloat16(b);
    return c.u;
}

__device__ __forceinline__ unsigned short f2bf(float x) {
    union { __hip_bfloat16 h; unsigned short s; } c;
    c.h = __float2bfloat16(x);
    return c.s;
}

// ---------------- CSR build ----------------

__global__ __launch_bounds__(256) void bin_count(const int* __restrict__ dst,
                                                 int* __restrict__ bin_counts,
                                                 int n_edges, int nb) {
    __shared__ int hist[MAX_BINS];
    const int t = threadIdx.x;
    for (int i = t; i < nb; i += 256) hist[i] = 0;
    __syncthreads();
    const int n4 = n_edges >> 2;
    for (int i = blockIdx.x * 256 + t; i < n4; i += gridDim.x * 256) {
        int4 d = ((const int4*)dst)[i];
        atomicAdd(&hist[d.x >> BIN_SHIFT], 1);
        atomicAdd(&hist[d.y >> BIN_SHIFT], 1);
        atomicAdd(&hist[d.z >> BIN_SHIFT], 1);
        atomicAdd(&hist[d.w >> BIN_SHIFT], 1);
    }
    if (blockIdx.x == 0 && t < (n_edges & 3))
        atomicAdd(&hist[dst[n4 * 4 + t] >> BIN_SHIFT], 1);
    __syncthreads();
    for (int i = t; i < nb; i += 256) {
        int h = hist[i];
        if (h) atomicAdd(&bin_counts[i], h);
    }
}

__global__ __launch_bounds__(512) void bin_scan(const int* __restrict__ bin_counts,
                                                int* __restrict__ bin_offsets,
                                                int* __restrict__ bin_cursor,
                                                int* __restrict__ offsets,
                                                int nb, int n_nodes, int n_edges) {
    __shared__ int sc[512];
    const int t = threadIdx.x;
    const int v = (t < nb) ? bin_counts[t] : 0;
    sc[t] = v;
    __syncthreads();
    for (int off = 1; off < 512; off <<= 1) {
        int u = (t >= off) ? sc[t - off] : 0;
        __syncthreads();
        sc[t] += u;
        __syncthreads();
    }
    if (t <= nb) {
        int e = (t < nb) ? (sc[t] - v) : n_edges;
        bin_offsets[t] = e;
        if (t < nb) bin_cursor[t] = e;
    }
    if (t == 0) offsets[n_nodes] = n_edges;
}

__global__ __launch_bounds__(256) void bin_scatter(const int* __restrict__ src,
                                                   const int* __restrict__ dst,
                                                   int* __restrict__ bin_cursor,
                                                   int* __restrict__ ebuf,
                                                   int n_edges, int nb) {
    __shared__ int hist[MAX_BINS];
    __shared__ int cur[MAX_BINS];
    const int t = threadIdx.x;
    const int lo = blockIdx.x * SCAT_TILE;
    const int hi = min(lo + SCAT_TILE, n_edges);
    for (int i = t; i < nb; i += 256) hist[i] = 0;
    __syncthreads();
    for (int i = lo + t; i < hi; i += 256) atomicAdd(&hist[dst[i] >> BIN_SHIFT], 1);
    __syncthreads();
    for (int i = t; i < nb; i += 256) {
        int h = hist[i];
        cur[i] = h ? atomicAdd(&bin_cursor[i], h) : 0;
    }
    __syncthreads();
    for (int i = lo + t; i < hi; i += 256) {
        int d = dst[i];
        int b = d >> BIN_SHIFT;
        int pos = atomicAdd(&cur[b], 1);
        ebuf[pos] = ((d & 255) << 24) | src[i];
    }
}

__global__ __launch_bounds__(256) void csr_build(const int* __restrict__ ebuf,
                                                 const int* __restrict__ bin_offsets,
                                                 int* __restrict__ offsets,
                                                 int* __restrict__ csr,
                                                 int n_nodes) {
    __shared__ int cnt[256];
    __shared__ int sc[256];
    __shared__ int cur[256];
    const int b = blockIdx.x;
    const int t = threadIdx.x;
    const int lo = bin_offsets[b];
    const int hi = bin_offsets[b + 1];
    cnt[t] = 0;
    __syncthreads();
    for (int e = lo + t; e < hi; e += 256)
        atomicAdd(&cnt[((unsigned)ebuf[e]) >> 24], 1);
    __syncthreads();
    const int x = cnt[t];
    sc[t] = x;
    __syncthreads();
    for (int off = 1; off < 256; off <<= 1) {
        int u = (t >= off) ? sc[t - off] : 0;
        __syncthreads();
        sc[t] += u;
        __syncthreads();
    }
    const int start = lo + sc[t] - x;
    cur[t] = start;
    const int node = (b << BIN_SHIFT) + t;
    if (node < n_nodes) offsets[node] = start;
    __syncthreads();
    for (int e = lo + t; e < hi; e += 256) {
        int p = ebuf[e];
        int dl = ((unsigned)p) >> 24;
        int pos = atomicAdd(&cur[dl], 1);
        csr[pos] = p & 0x00FFFFFF;
    }
}

// ---------------- prep_w: Wt[n][k] (bf16) = W[k][n] (f32), 128x128 x2 ----------

__global__ __launch_bounds__(256) void prep_w(const float* __restrict__ W0,
                                              const float* __restrict__ W1,
                                              unsigned short* __restrict__ Wt0,
                                              unsigned short* __restrict__ Wt1) {
    int i = blockIdx.x * 256 + threadIdx.x;  // 0..32767
    const float* W = (i < 16384) ? W0 : W1;
    unsigned short* Wt = (i < 16384) ? Wt0 : Wt1;
    int ii = i & 16383;
    int k = ii >> 7, nn = ii & 127;
    Wt[nn * 128 + k] = f2bf(W[ii]);
}

// ------- agg128_bf16: Y[n,128](bf16) = relu(sum_e X[csr[e],128](bf16) + bias) ----
// 16 lanes per node (uint4 = 8 bf16 each), 16 nodes per 256-thread block.

__global__ __launch_bounds__(256) void agg128_bf16(const unsigned* __restrict__ X,
                                                   const int* __restrict__ offsets,
                                                   const int* __restrict__ csr_src,
                                                   const float* __restrict__ bias,
                                                   unsigned* __restrict__ Yb, int n) {
    const int t = threadIdx.x;
    const int g = t >> 4;
    const int lane = t & 15;
    const int node = blockIdx.x * 16 + g;
    if (node >= n) return;
    const int e0 = offsets[node];
    const int e1 = offsets[node + 1];
    const int cu = lane * 4;
    float acc[8] = {0.f, 0.f, 0.f, 0.f, 0.f, 0.f, 0.f, 0.f};
    int e = e0;
    for (; e + 3 < e1; e += 4) {
        int s0 = csr_src[e];
        int s1 = csr_src[e + 1];
        int s2 = csr_src[e + 2];
        int s3 = csr_src[e + 3];
        uint4 v0 = *(const uint4*)(X + (size_t)s0 * 64 + cu);
        uint4 v1 = *(const uint4*)(X + (size_t)s1 * 64 + cu);
        uint4 v2 = *(const uint4*)(X + (size_t)s2 * 64 + cu);
        uint4 v3 = *(const uint4*)(X + (size_t)s3 * 64 + cu);
        bf16x8_add(acc, v0);
        bf16x8_add(acc, v1);
        bf16x8_add(acc, v2);
        bf16x8_add(acc, v3);
    }
    for (; e < e1; ++e) {
        int s0 = csr_src[e];
        uint4 v0 = *(const uint4*)(X + (size_t)s0 * 64 + cu);
        bf16x8_add(acc, v0);
    }
    float4 b0 = *(const float4*)(bias + lane * 8);
    float4 b1 = *(const float4*)(bias + lane * 8 + 4);
    acc[0] = fmaxf(acc[0] + b0.x, 0.f);
    acc[1] = fmaxf(acc[1] + b0.y, 0.f);
    acc[2] = fmaxf(acc[2] + b0.z, 0.f);
    acc[3] = fmaxf(acc[3] + b0.w, 0.f);
    acc[4] = fmaxf(acc[4] + b1.x, 0.f);
    acc[5] = fmaxf(acc[5] + b1.y, 0.f);
    acc[6] = fmaxf(acc[6] + b1.z, 0.f);
    acc[7] = fmaxf(acc[7] + b1.w, 0.f);
    *(uint4*)(Yb + (size_t)node * 64 + lane * 4) =
        make_uint4(pack_bf16(acc[0], acc[1]), pack_bf16(acc[2], acc[3]),
                   pack_bf16(acc[4], acc[5]), pack_bf16(acc[6], acc[7]));
}

// ------- agg40_bf16: out[n,40](f32) = sum X[csr[e],40](bf16) + bias ----------

__global__ __launch_bounds__(256) void agg40_bf16(const unsigned* __restrict__ X,
                                                  const int* __restrict__ offsets,
                                                  const int* __restrict__ csr_src,
                                                  const float* __restrict__ bias,
                                                  float* __restrict__ Y, int n) {
    const int t = threadIdx.x;
    const int g = t >> 3;
    const int lane = t & 7;
    const int node = blockIdx.x * 32 + g;
    if (node >= n) return;
    const int e0 = offsets[node];
    const int e1 = offsets[node + 1];
    const bool active = lane < 5;
    const int cu = lane * 4;
    float acc[8] = {0.f, 0.f, 0.f, 0.f, 0.f, 0.f, 0.f, 0.f};
    int e = e0;
    for (; e + 3 < e1; e += 4) {
        int s0 = csr_src[e];
        int s1 = csr_src[e + 1];
        int s2 = csr_src[e + 2];
        int s3 = csr_src[e + 3];
        if (active) {
            uint4 v0 = *(const uint4*)(X + (size_t)s0 * 20 + cu);
            uint4 v1 = *(const uint4*)(X + (size_t)s1 * 20 + cu);
            uint4 v2 = *(const uint4*)(X + (size_t)s2 * 20 + cu);
            uint4 v3 = *(const uint4*)(X + (size_t)s3 * 20 + cu);
            bf16x8_add(acc, v0);
            bf16x8_add(acc, v1);
            bf16x8_add(acc, v2);
            bf16x8_add(acc, v3);
        }
    }
    for (; e < e1; ++e) {
        int s0 = csr_src[e];
        if (active) {
            uint4 v0 = *(const uint4*)(X + (size_t)s0 * 20 + cu);
            bf16x8_add(acc, v0);
        }
    }
    if (active) {
        float4 b0 = *(const float4*)(bias + lane * 8);
        float4 b1 = *(const float4*)(bias + lane * 8 + 4);
        float* yp = Y + (size_t)node * 40 + lane * 8;
        *(float4*)yp = make_float4(acc[0] + b0.x, acc[1] + b0.y,
                                   acc[2] + b0.z, acc[3] + b0.w);
        *(float4*)(yp + 4) = make_float4(acc[4] + b1.x, acc[5] + b1.y,
                                         acc[6] + b1.z, acc[7] + b1.w);
    }
}

// ------- mm128_mfma: C[N,128](bf16) = A[N,128] @ W[128,128], MFMA 16x16x32 -----
// 128 rows/block, 4 waves x 32 rows. Wt (global, [n][k] bf16) staged in LDS with
// 272B row pitch (bank-stride 4 -> conflict-free b128 reads). A-frags direct from
// global (each wave instr covers full 64B lines). C bounced through same LDS.

template <bool AF32>
__global__ __launch_bounds__(256) void mm128_mfma(const void* __restrict__ Av,
                                                  const unsigned* __restrict__ Wt,
                                                  unsigned* __restrict__ C, int n) {
    __shared__ __align__(16) unsigned char smem[128 * 272];  // 34 KB, W then C
    const int t = threadIdx.x;
    const int w = t >> 6;
    const int l = t & 63;
    const int rl = l & 15;   // row (A) / col (B) within fragment
    const int g = l >> 4;    // k-group
    const int row0 = blockIdx.x * 128;

    // stage Wt -> LDS (padded rows)
    for (int i = t; i < 2048; i += 256) {
        int nn = i >> 4, j = i & 15;
        *(uint4*)(smem + nn * 272 + j * 16) = *(const uint4*)(Wt + nn * 64 + j * 4);
    }

    // A fragments: 2 row-tiles x 4 k-chunks, 8 contiguous bf16 per lane
    bf16x8_t a[2][4];
#pragma unroll
    for (int rt = 0; rt < 2; ++rt) {
        const int row = row0 + w * 32 + rt * 16 + rl;
        const bool ok = row < n;
#pragma unroll
        for (int kc = 0; kc < 4; ++kc) {
            union { uint4 u; bf16x8_t h; } pk;
            pk.u = make_uint4(0, 0, 0, 0);
            if (AF32) {
                if (ok) {
                    const float* ap = (const float*)Av + (size_t)row * 128 + kc * 32 + g * 8;
                    float4 lo = *(const float4*)ap;
                    float4 hi = *(const float4*)(ap + 4);
                    pk.u = make_uint4(pack_bf16(lo.x, lo.y), pack_bf16(lo.z, lo.w),
                                      pack_bf16(hi.x, hi.y), pack_bf16(hi.z, hi.w));
                }
            } else {
                if (ok)
                    pk.u = *(const uint4*)((const unsigned*)Av + (size_t)row * 64 + kc * 16 + g * 4);
            }
            a[rt][kc] = pk.h;
        }
    }
    __syncthreads();

    f32x4_t acc[2][8];
#pragma unroll
    for (int rt = 0; rt < 2; ++rt)
#pragma unroll
        for (int ct = 0; ct < 8; ++ct)
            acc[rt][ct] = (f32x4_t){0.f, 0.f, 0.f, 0.f};

#pragma unroll
    for (int ct = 0; ct < 8; ++ct) {
#pragma unroll
        for (int kc = 0; kc < 4; ++kc) {
            bf16x8_t b = *(const bf16x8_t*)(smem + (ct * 16 + rl) * 272 + kc * 64 + g * 16);
            acc[0][ct] = __builtin_amdgcn_mfma_f32_16x16x32_bf16(a[0][kc], b, acc[0][ct], 0, 0, 0);
            acc[1][ct] = __builtin_amdgcn_mfma_f32_16x16x32_bf16(a[1][kc], b, acc[1][ct], 0, 0, 0);
        }
    }
    __syncthreads();  // done with W region

    // acc -> LDS bf16 (C/D layout: col = lane&15, row = (lane>>4)*4 + reg)
#pragma unroll
    for (int rt = 0; rt < 2; ++rt)
#pragma unroll
        for (int ct = 0; ct < 8; ++ct)
#pragma unroll
            for (int r = 0; r < 4; ++r) {
                int lr = w * 32 + rt * 16 + g * 4 + r;
                int col = ct * 16 + rl;
                *(unsigned short*)(smem + lr * 272 + col * 2) = f2bf(acc[rt][ct][r]);
            }
    __syncthreads();

    // coalesced readout
    for (int i = t; i < 2048; i += 256) {
        int r = i >> 4, j = i & 15;
        int row = row0 + r;
        if (row < n)
            *(uint4*)(C + (size_t)row * 64 + j * 4) = *(const uint4*)(smem + r * 272 + j * 16);
    }
}

// ---------------- mm40: C[N,40](bf16) = A[N,128](bf16) @ W[128,40](f32) --------

__global__ __launch_bounds__(256) void mm40_kernel(const unsigned* __restrict__ Ab,
                                                   const float* __restrict__ W,
                                                   unsigned* __restrict__ C, int n) {
    __shared__ float Wl[128][40];
    __shared__ __align__(16) float Al[32][132];
    __shared__ __align__(16) float Cl[32][40];
    const int t = threadIdx.x;
    const int row0 = blockIdx.x * 32;

    for (int i = t; i < 128 * 40; i += 256) Wl[i / 40][i % 40] = W[i];
    for (int i = t; i < 512; i += 256) {
        int r = i >> 4, j = i & 15;
        int row = row0 + r;
        uint4 v = make_uint4(0, 0, 0, 0);
        if (row < n) v = *(const uint4*)(Ab + (size_t)row * 64 + j * 4);
        float* d = &Al[r][j * 8];
        d[0] = __uint_as_float(v.x << 16); d[1] = __uint_as_float(v.x & 0xffff0000u);
        d[2] = __uint_as_float(v.y << 16); d[3] = __uint_as_float(v.y & 0xffff0000u);
        d[4] = __uint_as_float(v.z << 16); d[5] = __uint_as_float(v.z & 0xffff0000u);
        d[6] = __uint_as_float(v.w << 16); d[7] = __uint_as_float(v.w & 0xffff0000u);
    }
    __syncthreads();

    const int rl = t >> 3;
    const int c0 = (t & 7) * 5;
    float acc[5] = {0.f, 0.f, 0.f, 0.f, 0.f};
    for (int k = 0; k < 128; ++k) {
        float a = Al[rl][k];
#pragma unroll
        for (int j = 0; j < 5; ++j) acc[j] += a * Wl[k][c0 + j];
    }
#pragma unroll
    for (int j = 0; j < 5; ++j) Cl[rl][c0 + j] = acc[j];
    __syncthreads();

    for (int i = t; i < 160; i += 256) {
        int r = i / 5, q = i % 5;
        int row = row0 + r;
        if (row >= n) continue;
        const float* s = &Cl[r][q * 8];
        uint4 o = make_uint4(pack_bf16(s[0], s[1]), pack_bf16(s[2], s[3]),
                             pack_bf16(s[4], s[5]), pack_bf16(s[6], s[7]));
        *(uint4*)(C + (size_t)row * 20 + q * 4) = o;
    }
}

// ---------------- launch ----------------

extern "C" void kernel_launch(void* const* d_in, const int* in_sizes, int n_in,
                              void* d_out, int out_size, void* d_ws, size_t ws_size,
                              hipStream_t stream) {
    const float* features = (const float*)d_in[0];
    const int* src = (const int*)d_in[1];
    const int* dst = (const int*)d_in[2];
    const float* W0 = (const float*)d_in[3];
    const float* b0 = (const float*)d_in[4];
    const float* W1 = (const float*)d_in[5];
    const float* b1 = (const float*)d_in[6];
    const float* W2 = (const float*)d_in[7];
    const float* b2 = (const float*)d_in[8];
    float* out = (float*)d_out;

    const int n_nodes = in_sizes[0] / FEAT;
    const int n_edges = in_sizes[1];
    const int nb = (n_nodes + 255) >> BIN_SHIFT;

    char* p = (char*)d_ws;
    auto alloc = [&](size_t bytes) {
        char* q = p;
        p += (bytes + 255) & ~(size_t)255;
        return q;
    };
    unsigned* bufA  = (unsigned*)alloc((size_t)n_nodes * FEAT * 2);  // bf16 [N,128]
    unsigned* bufB  = (unsigned*)alloc((size_t)n_nodes * FEAT * 2);  // bf16 [N,128]
    int* offsets    = (int*)alloc((size_t)(n_nodes + 1) * 4);
    int* csr        = (int*)alloc((size_t)n_edges * 4);
    int* ebuf       = (int*)alloc((size_t)n_edges * 4);
    int* bin_counts = (int*)alloc(MAX_BINS * 4);
    int* bin_offs   = (int*)alloc((MAX_BINS + 1) * 4);
    int* bin_cursor = (int*)alloc(MAX_BINS * 4);
    unsigned short* Wt0 = (unsigned short*)alloc(16384 * 2);
    unsigned short* Wt1 = (unsigned short*)alloc(16384 * 2);
    unsigned* bufC  = bufA;  // alias: bf16 [N,40] fits in bufA's region

    // weight transpose (independent of CSR chain)
    prep_w<<<128, 256, 0, stream>>>(W0, W1, Wt0, Wt1);

    // CSR build (binned)
    hipMemsetAsync(bin_counts, 0, MAX_BINS * 4, stream);
    bin_count<<<256, 256, 0, stream>>>(dst, bin_counts, n_edges, nb);
    bin_scan<<<1, 512, 0, stream>>>(bin_counts, bin_offs, bin_cursor, offsets,
                                    nb, n_nodes, n_edges);
    bin_scatter<<<(n_edges + SCAT_TILE - 1) / SCAT_TILE, 256, 0, stream>>>(
        src, dst, bin_cursor, ebuf, n_edges, nb);
    csr_build<<<nb, 256, 0, stream>>>(ebuf, bin_offs, offsets, csr, n_nodes);

    const int mmf_grid = (n_nodes + 127) / 128;
    const int mm40_grid = (n_nodes + 31) / 32;
    const int agg_grid = (n_nodes + 15) / 16;
    const int agg40_grid = (n_nodes + 31) / 32;

    // layer 0
    mm128_mfma<true><<<mmf_grid, 256, 0, stream>>>(features, (const unsigned*)Wt0, bufA, n_nodes);
    agg128_bf16<<<agg_grid, 256, 0, stream>>>(bufA, offsets, csr, b0, bufB, n_nodes);
    // layer 1
    mm128_mfma<false><<<mmf_grid, 256, 0, stream>>>(bufB, (const unsigned*)Wt1, bufA, n_nodes);
    agg128_bf16<<<agg_grid, 256, 0, stream>>>(bufA, offsets, csr, b1, bufB, n_nodes);
    // layer 2: matmul-first (128->40), then aggregate + bias
    mm40_kernel<<<mm40_grid, 256, 0, stream>>>(bufB, W2, bufC, n_nodes);
    agg40_bf16<<<agg40_grid, 256, 0, stream>>>(bufC, offsets, csr, b2, out, n_nodes);
}